// Round 8
// baseline (158.750 us; speedup 1.0000x reference)
//
#include <hip/hip_runtime.h>
#include <hip/hip_cooperative_groups.h>
#include <math.h>

namespace cg = cooperative_groups;

// Problem constants:
// x: (32, 256, 112, 112) fp32, W: (1, 2, 7, 7) fp32, out: (32, 1, 112, 112) fp32
#define BATCH 32
#define CH    256
#define HH    112
#define WW    112
#define HW    (HH * WW)     // 12544
#define HW4   (HW / 4)      // 3136 = 7 * 448

#define NBX   7             // stripes per plane
#define CHUNK 448           // float4s per stripe (= 16 full rows)
#define ROWS  16            // rows per stripe

typedef float f32x4 __attribute__((ext_vector_type(4)));

// ---------------------------------------------------------------------------
// Fused kernel (cooperative): phase 1 pools (channel mean+max, the proven r6
// structure: 7 KiB contiguous/c-step, per-block channel-start stagger,
// nontemporal x loads); grid.sync(); phase 2 convolves each block's OWN
// 16-row stripe (halo rows +-3 come from neighbor blocks via L2 after the
// sync). Eliminates the separate conv dispatch (~5-7 us tail).
// ---------------------------------------------------------------------------
__global__ __launch_bounds__(448) void sa_fused_kernel(
    const f32x4* __restrict__ x4,
    f32x4* __restrict__ avg4,     // workspace [BATCH][HW4]
    f32x4* __restrict__ max4,     // workspace [BATCH][HW4]
    const float* __restrict__ wt, // [2][7][7]
    float* __restrict__ out)
{
    __shared__ float t0[22][120];   // avg halo tile (22 rows x 118 used)
    __shared__ float t1[22][120];   // max halo tile
    __shared__ float w[2][49];

    int tid = threadIdx.x;
    int blk = blockIdx.x;           // 0..223
    int b   = blk / NBX;            // batch
    int bx  = blk - b * NBX;        // stripe within plane
    int q   = bx * CHUNK + tid;     // float4 index within plane

    // ---------------- phase 1: channel-wise mean + max ----------------
    const f32x4* p = x4 + (size_t)b * (CH * HW4) + q;
    int c0 = (bx * 37 + b * 11) & (CH - 1);   // DRAM channel-phase stagger

    f32x4 s = (f32x4){0.f, 0.f, 0.f, 0.f};
    f32x4 m = (f32x4){-INFINITY, -INFINITY, -INFINITY, -INFINITY};

    #pragma unroll 8
    for (int cc = 0; cc < CH; ++cc) {
        int c = cc + c0;
        c -= (c >= CH) ? CH : 0;
        f32x4 v = __builtin_nontemporal_load(p + (size_t)c * HW4);
        s.x += v.x; s.y += v.y; s.z += v.z; s.w += v.w;
        m.x = fmaxf(m.x, v.x);
        m.y = fmaxf(m.y, v.y);
        m.z = fmaxf(m.z, v.z);
        m.w = fmaxf(m.w, v.w);
    }

    const float inv = 1.0f / (float)CH;
    f32x4 a;
    a.x = s.x * inv; a.y = s.y * inv; a.z = s.z * inv; a.w = s.w * inv;

    int g = b * HW4 + q;
    avg4[g] = a;    // plain stores: conv phase wants these L2-resident
    max4[g] = m;

    __threadfence();            // agent-scope release of the pooled planes
    cg::this_grid().sync();     // all stripes complete + acquire

    // ---------------- phase 2: 7x7 conv + sigmoid on own stripe ----------------
    if (tid < 98) w[tid / 49][tid % 49] = wt[tid];

    const float* ap = (const float*)avg4 + (size_t)b * HW;
    const float* mp = (const float*)max4 + (size_t)b * HW;
    int r0 = bx * ROWS;

    for (int idx = tid; idx < 22 * 118; idx += 448) {
        int iy = idx / 118;
        int ix = idx - iy * 118;
        int gy = r0 + iy - 3;
        int gx = ix - 3;
        bool ok = (gy >= 0) && (gy < HH) && (gx >= 0) && (gx < WW);
        int gofs = gy * WW + gx;
        t0[iy][ix] = ok ? ap[gofs] : 0.0f;
        t1[iy][ix] = ok ? mp[gofs] : 0.0f;
    }
    __syncthreads();

    // each thread: 4 consecutive pixels (112 % 4 == 0 -> never crosses rows)
    int row = (tid * 4) / WW;       // 0..15
    int col = (tid * 4) % WW;       // 0..108, step 4

    float acc0 = 0.f, acc1 = 0.f, acc2 = 0.f, acc3 = 0.f;
    #pragma unroll
    for (int i = 0; i < 7; ++i) {
        #pragma unroll
        for (int k = 0; k < 7; ++k) {
            float w0 = w[0][i * 7 + k];
            float w1 = w[1][i * 7 + k];
            const float* r0p = &t0[row + i][col + k];
            const float* r1p = &t1[row + i][col + k];
            acc0 += w0 * r0p[0] + w1 * r1p[0];
            acc1 += w0 * r0p[1] + w1 * r1p[1];
            acc2 += w0 * r0p[2] + w1 * r1p[2];
            acc3 += w0 * r0p[3] + w1 * r1p[3];
        }
    }

    f32x4 o;
    o.x = 1.0f / (1.0f + expf(-acc0));
    o.y = 1.0f / (1.0f + expf(-acc1));
    o.z = 1.0f / (1.0f + expf(-acc2));
    o.w = 1.0f / (1.0f + expf(-acc3));
    *((f32x4*)(out + (size_t)b * HW + (size_t)(r0 + row) * WW + col)) = o;
}

// ---------------------------------------------------------------------------
extern "C" void kernel_launch(void* const* d_in, const int* in_sizes, int n_in,
                              void* d_out, int out_size, void* d_ws, size_t ws_size,
                              hipStream_t stream)
{
    const f32x4* x4   = (const f32x4*)d_in[0];
    const float* wt   = (const float*)d_in[1];
    float*       out  = (float*)d_out;

    f32x4* avg4 = (f32x4*)d_ws;                       // [BATCH][HW4]
    f32x4* max4 = avg4 + (size_t)BATCH * HW4;         // [BATCH][HW4]

    void* args[5] = { (void*)&x4, (void*)&avg4, (void*)&max4,
                      (void*)&wt, (void*)&out };

    hipLaunchCooperativeKernel((const void*)sa_fused_kernel,
                               dim3(BATCH * NBX), dim3(CHUNK),
                               args, 0, stream);
}

// Round 9
// 77.156 us; speedup vs baseline: 2.0575x; 2.0575x over previous
//
#include <hip/hip_runtime.h>
#include <math.h>

// Problem constants (from reference):
// x: (32, 256, 112, 112) fp32, W: (1, 2, 7, 7) fp32, out: (32, 1, 112, 112) fp32
#define BATCH 32
#define CH    256
#define HH    112
#define WW    112
#define HW    (HH * WW)     // 12544
#define HW4   (HW / 4)      // 3136 = 8 * 392

#define NBX   8             // stripes per plane  -> 8*32 = 256 blocks = 1/CU
#define CHUNK 392           // float4s per stripe (= 14 rows of 112)

// native clang vector type — accepted by __builtin_nontemporal_load
typedef float f32x4 __attribute__((ext_vector_type(4)));

// ---------------------------------------------------------------------------
// Kernel 1: channel-wise mean + max reduction.
// r6 structure (best: 76.7us) with ONE change: grid 224 -> 256 blocks so ALL
// CUs stream. Evidence: pool per-active-CU rate 26.8 GB/s == fill kernels'
// 26.6 GB/s/CU -> we are per-CU-limited, and 32 idle CUs are the gap.
// Stripe shrinks 16->14 rows (448->392 float4, 7->6.1 KiB runs: ~2% penalty
// per the r0/r1/r3 run-length curve, outweighed by +14% CU count).
// Keeps: per-block channel-start stagger (decorrelate HBM channel phase),
// nontemporal x loads (don't thrash L3), unroll 8. Drops: r7 barrier (neutral).
// ---------------------------------------------------------------------------
__global__ __launch_bounds__(CHUNK) void sa_pool_kernel(
    const f32x4* __restrict__ x4,
    f32x4* __restrict__ avg4,
    f32x4* __restrict__ max4)
{
    int tid = threadIdx.x;
    int b   = blockIdx.y;
    int q   = blockIdx.x * CHUNK + tid;   // float4 index within the HxW plane

    const f32x4* p = x4 + (size_t)b * (CH * HW4) + q;

    // stagger channel start per block to spread DRAM channel phase
    int c0 = (blockIdx.x * 37 + blockIdx.y * 11) & (CH - 1);

    f32x4 s = (f32x4){0.f, 0.f, 0.f, 0.f};
    f32x4 m = (f32x4){-INFINITY, -INFINITY, -INFINITY, -INFINITY};

    #pragma unroll 8
    for (int cc = 0; cc < CH; ++cc) {
        int c = cc + c0;
        c -= (c >= CH) ? CH : 0;
        f32x4 v = __builtin_nontemporal_load(p + (size_t)c * HW4);
        s.x += v.x; s.y += v.y; s.z += v.z; s.w += v.w;
        m.x = fmaxf(m.x, v.x);
        m.y = fmaxf(m.y, v.y);
        m.z = fmaxf(m.z, v.z);
        m.w = fmaxf(m.w, v.w);
    }

    const float inv = 1.0f / (float)CH;
    f32x4 a;
    a.x = s.x * inv; a.y = s.y * inv; a.z = s.z * inv; a.w = s.w * inv;

    int g = b * HW4 + q;
    avg4[g] = a;
    max4[g] = m;
}

// ---------------------------------------------------------------------------
// Kernel 2: 7x7 conv (2 in-ch -> 1 out-ch, pad 3) + sigmoid (unchanged r6).
// 16x16 output tile / block; halo tile 22x22 per channel in LDS; weights in
// LDS. 112/16 = 7 exactly -> no output bounds checks.
// ---------------------------------------------------------------------------
#define TILE 16
#define TW   (TILE + 6)     // 22

__global__ __launch_bounds__(256) void sa_conv_kernel(
    const float* __restrict__ avgp,
    const float* __restrict__ maxp,
    const float* __restrict__ wt,    // [2][7][7] flat (O=1, OIHW)
    float* __restrict__ out)
{
    __shared__ float t0[TW][TW];
    __shared__ float t1[TW][TW];
    __shared__ float w[2][49];

    int tid = threadIdx.x;
    int b   = blockIdx.z;
    int ty0 = blockIdx.y * TILE;
    int tx0 = blockIdx.x * TILE;

    if (tid < 98) w[tid / 49][tid % 49] = wt[tid];

    const float* ap = avgp + b * HW;
    const float* mp = maxp + b * HW;

    for (int idx = tid; idx < TW * TW; idx += 256) {
        int iy = idx / TW;
        int ix = idx - iy * TW;
        int gy = ty0 + iy - 3;
        int gx = tx0 + ix - 3;
        bool ok = (gy >= 0) && (gy < HH) && (gx >= 0) && (gx < WW);
        int gofs = gy * WW + gx;
        t0[iy][ix] = ok ? ap[gofs] : 0.0f;
        t1[iy][ix] = ok ? mp[gofs] : 0.0f;
    }
    __syncthreads();

    int oy = tid >> 4;          // 0..15
    int ox = tid & 15;          // 0..15

    float acc = 0.0f;
    #pragma unroll
    for (int i = 0; i < 7; ++i) {
        #pragma unroll
        for (int j = 0; j < 7; ++j) {
            acc += w[0][i * 7 + j] * t0[oy + i][ox + j];
            acc += w[1][i * 7 + j] * t1[oy + i][ox + j];
        }
    }

    float y = 1.0f / (1.0f + expf(-acc));
    out[b * HW + (ty0 + oy) * WW + (tx0 + ox)] = y;
}

// ---------------------------------------------------------------------------
extern "C" void kernel_launch(void* const* d_in, const int* in_sizes, int n_in,
                              void* d_out, int out_size, void* d_ws, size_t ws_size,
                              hipStream_t stream)
{
    const float* x  = (const float*)d_in[0];
    const float* wt = (const float*)d_in[1];
    float* out = (float*)d_out;

    // workspace: avg plane then max plane, each BATCH*HW floats (1.6 MB each)
    float* avgp = (float*)d_ws;
    float* maxp = avgp + (size_t)BATCH * HW;

    // Kernel 1: 8 x 32 = 256 blocks (1 per CU) of 392 threads
    dim3 grid1(NBX, BATCH);
    sa_pool_kernel<<<grid1, CHUNK, 0, stream>>>(
        (const f32x4*)x, (f32x4*)avgp, (f32x4*)maxp);

    // Kernel 2: 7x7 tiles, 32 batches
    dim3 grid2(WW / TILE, HH / TILE, BATCH);
    sa_conv_kernel<<<grid2, 256, 0, stream>>>(avgp, maxp, wt, out);
}

// Round 10
// 71.854 us; speedup vs baseline: 2.2093x; 1.0738x over previous
//
#include <hip/hip_runtime.h>
#include <math.h>

// Problem constants (from reference):
// x: (32, 256, 112, 112) fp32, W: (1, 2, 7, 7) fp32, out: (32, 1, 112, 112) fp32
#define BATCH 32
#define CH    256
#define HH    112
#define WW    112
#define HW    (HH * WW)     // 12544
#define HW4   (HW / 4)      // 3136 = 7 * 448

#define NBX   7             // stripes per plane
#define CHUNK 448           // float4s per stripe (= 16 rows); also block size
#define ROWS  16            // rows per stripe

// native clang vector type — accepted by __builtin_nontemporal_load
typedef float f32x4 __attribute__((ext_vector_type(4)));

// ---------------------------------------------------------------------------
// Kernel 1: channel-wise mean + max reduction — UNCHANGED from r6 (76.7us).
// 224 blocks x 448 threads; 7 KiB contiguous per c-step; per-block channel
// stagger; nontemporal loads. Pool BW measured at ~6.0 TB/s = device limit
// for this pattern (CU-count and pacing levers falsified r7/r9).
// ---------------------------------------------------------------------------
__global__ __launch_bounds__(CHUNK) void sa_pool_kernel(
    const f32x4* __restrict__ x4,
    f32x4* __restrict__ avg4,
    f32x4* __restrict__ max4)
{
    int tid = threadIdx.x;
    int b   = blockIdx.y;
    int q   = blockIdx.x * CHUNK + tid;   // float4 index within the HxW plane

    const f32x4* p = x4 + (size_t)b * (CH * HW4) + q;

    // stagger channel start per block to spread DRAM channel phase
    int c0 = (blockIdx.x * 37 + blockIdx.y * 11) & (CH - 1);

    f32x4 s = (f32x4){0.f, 0.f, 0.f, 0.f};
    f32x4 m = (f32x4){-INFINITY, -INFINITY, -INFINITY, -INFINITY};

    #pragma unroll 8
    for (int cc = 0; cc < CH; ++cc) {
        int c = cc + c0;
        c -= (c >= CH) ? CH : 0;
        f32x4 v = __builtin_nontemporal_load(p + (size_t)c * HW4);
        s.x += v.x; s.y += v.y; s.z += v.z; s.w += v.w;
        m.x = fmaxf(m.x, v.x);
        m.y = fmaxf(m.y, v.y);
        m.z = fmaxf(m.z, v.z);
        m.w = fmaxf(m.w, v.w);
    }

    const float inv = 1.0f / (float)CH;
    f32x4 a;
    a.x = s.x * inv; a.y = s.y * inv; a.z = s.z * inv; a.w = s.w * inv;

    int g = b * HW4 + q;
    avg4[g] = a;
    max4[g] = m;
}

// ---------------------------------------------------------------------------
// Kernel 2 (REWORKED): 7x7 conv + sigmoid, stripe-per-block.
// 224 blocks x 448 threads (matches pool shape). Each block: one 16-row x
// 112-col stripe, 22x118 halo in LDS, 4 consecutive px per thread.
// vs r6's 1568 tiny blocks: 7x fewer blocks, halo redundancy 89% -> 37%,
// 4x work per thread -> dispatch tail ~6-7us -> ~2-3us (theory).
// ---------------------------------------------------------------------------
__global__ __launch_bounds__(CHUNK) void sa_conv_kernel(
    const float* __restrict__ avgp,
    const float* __restrict__ maxp,
    const float* __restrict__ wt,    // [2][7][7] flat (O=1, OIHW)
    float* __restrict__ out)
{
    __shared__ float t0[22][120];   // avg halo tile (22 rows x 118 used)
    __shared__ float t1[22][120];   // max halo tile
    __shared__ float w[2][49];

    int tid = threadIdx.x;
    int b   = blockIdx.y;
    int r0  = blockIdx.x * ROWS;

    if (tid < 98) w[tid / 49][tid % 49] = wt[tid];

    const float* ap = avgp + (size_t)b * HW;
    const float* mp = maxp + (size_t)b * HW;

    for (int idx = tid; idx < 22 * 118; idx += CHUNK) {
        int iy = idx / 118;
        int ix = idx - iy * 118;
        int gy = r0 + iy - 3;
        int gx = ix - 3;
        bool ok = (gy >= 0) && (gy < HH) && (gx >= 0) && (gx < WW);
        int gofs = gy * WW + gx;
        t0[iy][ix] = ok ? ap[gofs] : 0.0f;
        t1[iy][ix] = ok ? mp[gofs] : 0.0f;
    }
    __syncthreads();

    // each thread: 4 consecutive pixels (112 % 4 == 0 -> never crosses rows)
    int row = (tid * 4) / WW;       // 0..15
    int col = (tid * 4) % WW;       // 0..108, step 4

    float acc0 = 0.f, acc1 = 0.f, acc2 = 0.f, acc3 = 0.f;
    #pragma unroll
    for (int i = 0; i < 7; ++i) {
        #pragma unroll
        for (int k = 0; k < 7; ++k) {
            float w0 = w[0][i * 7 + k];
            float w1 = w[1][i * 7 + k];
            const float* r0p = &t0[row + i][col + k];
            const float* r1p = &t1[row + i][col + k];
            acc0 += w0 * r0p[0] + w1 * r1p[0];
            acc1 += w0 * r0p[1] + w1 * r1p[1];
            acc2 += w0 * r0p[2] + w1 * r1p[2];
            acc3 += w0 * r0p[3] + w1 * r1p[3];
        }
    }

    f32x4 o;
    o.x = 1.0f / (1.0f + expf(-acc0));
    o.y = 1.0f / (1.0f + expf(-acc1));
    o.z = 1.0f / (1.0f + expf(-acc2));
    o.w = 1.0f / (1.0f + expf(-acc3));
    *((f32x4*)(out + (size_t)b * HW + (size_t)(r0 + row) * WW + col)) = o;
}

// ---------------------------------------------------------------------------
extern "C" void kernel_launch(void* const* d_in, const int* in_sizes, int n_in,
                              void* d_out, int out_size, void* d_ws, size_t ws_size,
                              hipStream_t stream)
{
    const float* x  = (const float*)d_in[0];
    const float* wt = (const float*)d_in[1];
    float* out = (float*)d_out;

    // workspace: avg plane then max plane, each BATCH*HW floats (1.6 MB each)
    float* avgp = (float*)d_ws;
    float* maxp = avgp + (size_t)BATCH * HW;

    // Kernel 1: 7 x 32 = 224 blocks of 448 threads
    dim3 grid1(NBX, BATCH);
    sa_pool_kernel<<<grid1, CHUNK, 0, stream>>>(
        (const f32x4*)x, (f32x4*)avgp, (f32x4*)maxp);

    // Kernel 2: 7 x 32 = 224 blocks of 448 threads (stripe conv)
    dim3 grid2(NBX, BATCH);
    sa_conv_kernel<<<grid2, CHUNK, 0, stream>>>(avgp, maxp, wt, out);
}